// Round 11
// baseline (4709.700 us; speedup 1.0000x reference)
//
#include <hip/hip_runtime.h>
#include <hip/hip_bf16.h>

#define SEQ   512
#define BATCH 128
#define VOCAB 30000
#define EDIM  256
#define HDIM  256
#define NT    9

// ---------------- K0b: detect mask storage dtype ----------------
__global__ void k_detect(const unsigned char* __restrict__ m, int* __restrict__ flag) {
    __shared__ int ok_sh;
    if (threadIdx.x == 0) ok_sh = 1;
    __syncthreads();
    int b = threadIdx.x;  // 128 threads, one row each
    const uint4* row = (const uint4*)(m + b * SEQ);
    int ok = 1, prev = 1;
    for (int i = 0; i < SEQ / 16; ++i) {
        uint4 v = row[i];
        unsigned w[4] = {v.x, v.y, v.z, v.w};
        #pragma unroll
        for (int wi = 0; wi < 4; ++wi) {
            #pragma unroll
            for (int j = 0; j < 4; ++j) {
                int byte = (w[wi] >> (8 * j)) & 255;
                if (byte > 1 || byte > prev) ok = 0;
                prev = byte;
            }
        }
    }
    if (!ok) atomicAnd(&ok_sh, 0);
    __syncthreads();
    if (threadIdx.x == 0) *flag = ok_sh;
}

// ---------------- K1: table[v][n] = embed[v] . Wcat[n] + bias[n] ----------------
__global__ __launch_bounds__(256) void k_table_gemm(
    const float* __restrict__ emb, const float* __restrict__ Wf,
    const float* __restrict__ Wb, const float* __restrict__ bf,
    const float* __restrict__ bb, float* __restrict__ table) {
    __shared__ __align__(16) float As[64][68];  // [k][m]
    __shared__ __align__(16) float Bs[64][68];  // [k][n]
    int t  = threadIdx.x;
    int tx = t & 15, ty = t >> 4;
    int n0 = blockIdx.x * 64;
    int v0 = blockIdx.y * 64;
    float acc[4][4] = {};
    for (int kc = 0; kc < 4; ++kc) {
        #pragma unroll
        for (int rr = 0; rr < 4; ++rr) {
            int slot = t + rr * 256;
            int m = slot >> 4, kq = slot & 15;
            int v = v0 + m;
            float4 a = (v < VOCAB)
                ? *(const float4*)&emb[v * EDIM + kc * 64 + kq * 4]
                : make_float4(0.f, 0.f, 0.f, 0.f);
            As[kq * 4 + 0][m] = a.x; As[kq * 4 + 1][m] = a.y;
            As[kq * 4 + 2][m] = a.z; As[kq * 4 + 3][m] = a.w;
            int n = n0 + m;
            const float* Wrow = (n < 1024) ? &Wf[n * 256] : &Wb[(n - 1024) * 256];
            float4 bvec = *(const float4*)&Wrow[kc * 64 + kq * 4];
            Bs[kq * 4 + 0][m] = bvec.x; Bs[kq * 4 + 1][m] = bvec.y;
            Bs[kq * 4 + 2][m] = bvec.z; Bs[kq * 4 + 3][m] = bvec.w;
        }
        __syncthreads();
        #pragma unroll
        for (int k = 0; k < 64; ++k) {
            float4 a = *(const float4*)&As[k][ty * 4];
            float4 b = *(const float4*)&Bs[k][tx * 4];
            acc[0][0] += a.x * b.x; acc[0][1] += a.x * b.y; acc[0][2] += a.x * b.z; acc[0][3] += a.x * b.w;
            acc[1][0] += a.y * b.x; acc[1][1] += a.y * b.y; acc[1][2] += a.y * b.z; acc[1][3] += a.y * b.w;
            acc[2][0] += a.z * b.x; acc[2][1] += a.z * b.y; acc[2][2] += a.z * b.z; acc[2][3] += a.z * b.w;
            acc[3][0] += a.w * b.x; acc[3][1] += a.w * b.y; acc[3][2] += a.w * b.z; acc[3][3] += a.w * b.w;
        }
        __syncthreads();
    }
    int n = n0 + tx * 4;
    const float* bi = (n < 1024) ? &bf[n] : &bb[n - 1024];
    float4 bias = *(const float4*)bi;
    #pragma unroll
    for (int i = 0; i < 4; ++i) {
        int v = v0 + ty * 4 + i;
        if (v < VOCAB) {
            float4 o;
            o.x = acc[i][0] + bias.x; o.y = acc[i][1] + bias.y;
            o.z = acc[i][2] + bias.z; o.w = acc[i][3] + bias.w;
            *(float4*)&table[(size_t)v * 2048 + n] = o;
        }
    }
}

// ---------------- K2: clustered LSTM, W LDS-resident, overlapped L3 exchange --
// 256 blocks x 1024 threads (16 waves, 4/SIMD). cluster = bid>>3, myb = bid&7.
// Dot map: lane = t&63 -> kh = lane&7 (k eighth), rlo = lane>>3; wave wv = t>>6
// -> bh = wv>>3 (batch quad), rhi = wv&7; rows r0 = rhi*8+rlo, r1 = r0+64;
// per thread: 2 rows x 4 batches x 8 k4. Partial sums over kh reduced via
// 3-stage shfl_xor within 8-lane groups; lane kh writes acc #kh to sh_g.
// LDS swizzles (2-way max bank aliasing, free):
//   W  at sh_w[row*256 + 4*(k4 ^ (k4>>3) ^ (row&63))]
//   h  at h_cur[b][4*(k4 ^ (k4>>3)) + sub]
// Exchange window (after single dot barrier), wave roles:
//   waves 0-3 : nonlin + hx publish (relaxed agent) + vmcnt(0) + LDS done-ctr;
//               t==0 spins ctr==4*(it+1) then publishes tag; then xg prefetch.
//   waves 4-7 : emission for h_{it-1} from h_em (linear stash made in dot phase)
//   waves 8-15: wave j polls tag[j] (j!=myb) then copies peer chunk j into h_cur
// 2 barriers/step. Tag protocol identical to r9/r10 (monotonic + 2-slot ring).
__global__ __launch_bounds__(1024) void k_lstm_cl(
    const int* __restrict__ ids, const float* __restrict__ Whhf,
    const float* __restrict__ Whhb, const float* __restrict__ table,
    const float* __restrict__ Wout, float* __restrict__ emp,
    float* hx, int* tagbuf) {
    extern __shared__ float sh_w[];            // 128 KB swizzled [128][256]
    __shared__ float h_cur[8][256];            // 8 KB (swizzled per-f4)
    __shared__ float h_em[256];                // 1 KB linear stash (batch myb)
    __shared__ float sh_g[8][128];             // 4 KB full gates
    __shared__ float wout_s[NT][257];
    __shared__ int   sh_ctr;

    const int t   = threadIdx.x;
    const int bid = blockIdx.x;
    const int cluster = bid >> 3;
    const int myb = bid & 7;
    const int dir = cluster & 1;
    const int oct = cluster >> 1;
    const int gbatch = oct * 8 + myb;

    const int lane = t & 63;
    const int wv   = t >> 6;
    const int kh   = lane & 7;
    const int rlo  = lane >> 3;
    const int bh   = wv >> 3;
    const int rhi  = wv & 7;
    const int r0   = rhi * 8 + rlo;            // 0..63
    const int r1   = r0 + 64;                  // 64..127

    const int nb = t >> 5, nd = t & 31;        // nonlin map (t<256)
    const int em = t - 256;                    // emission map (256<=t<400)
    const int etg = em >> 4, el = em & 15;
    const int cw = wv - 8;                     // copy wave peer id (wv>=8)

    const float* Whh = dir ? Whhb : Whhf;

    if (t == 0) sh_ctr = 0;
    for (int idx = t; idx < NT * 256; idx += 1024)
        wout_s[idx >> 8][idx & 255] = Wout[(idx >> 8) * 512 + dir * 256 + (idx & 255)];
    // stage W-slice, swizzled
    {
        int lr = t >> 3, part = t & 7;
        int grow = (lr >> 5) * 256 + myb * 32 + (lr & 31);
        const float4* src = (const float4*)(Whh + (size_t)grow * 256);
        #pragma unroll
        for (int i = 0; i < 8; ++i) {
            int k4 = part * 8 + i;
            float4 w = src[k4];
            int pw = k4 ^ (k4 >> 3) ^ (lr & 63);
            *(float4*)(sh_w + lr * 256 + 4 * pw) = w;
        }
    }
    for (int idx = t; idx < 2048; idx += 1024) ((float*)h_cur)[idx] = 0.f;
    float c_state = 0.f;
    __syncthreads();

    // xg prefetch for it=0 (nonlin threads hold i,f,g,o in regs)
    float xi = 0.f, xf = 0.f, xq = 0.f, xo = 0.f;
    if (t < 256) {
        int s0 = dir ? SEQ - 1 : 0;
        int id = ids[(oct * 8 + nb) * SEQ + s0];
        const float* tb = table + (size_t)id * 2048 + dir * 1024;
        int base = myb * 32 + nd;
        xi = tb[base]; xf = tb[256 + base]; xq = tb[512 + base]; xo = tb[768 + base];
    }

    #pragma unroll 1
    for (int it = 0; it < SEQ; ++it) {
        // ---- phase 1: stash h_em (linear) + dot partials ----
        if (t < 256) {
            int k4s = t >> 2;
            h_em[t] = h_cur[myb][4 * (k4s ^ (k4s >> 3)) + (t & 3)];
        }
        float a00 = 0.f, a01 = 0.f, a02 = 0.f, a03 = 0.f;
        float a10 = 0.f, a11 = 0.f, a12 = 0.f, a13 = 0.f;
        {
            const float* w0p = sh_w + r0 * 256;
            const float* w1p = sh_w + r1 * 256;
            const float* hb0 = h_cur[4 * bh + 0];
            const float* hb1 = h_cur[4 * bh + 1];
            const float* hb2 = h_cur[4 * bh + 2];
            const float* hb3 = h_cur[4 * bh + 3];
            #pragma unroll
            for (int j = 0; j < 8; ++j) {
                int k4 = kh * 8 + j;
                int ph = k4 ^ kh;                  // k4 ^ (k4>>3)
                float4 w0 = *(const float4*)(w0p + 4 * (ph ^ (r0 & 63)));
                float4 w1 = *(const float4*)(w1p + 4 * (ph ^ (r1 & 63)));
                float4 h0 = *(const float4*)(hb0 + 4 * ph);
                float4 h1 = *(const float4*)(hb1 + 4 * ph);
                float4 h2 = *(const float4*)(hb2 + 4 * ph);
                float4 h3 = *(const float4*)(hb3 + 4 * ph);
                a00 += w0.x*h0.x + w0.y*h0.y + w0.z*h0.z + w0.w*h0.w;
                a01 += w0.x*h1.x + w0.y*h1.y + w0.z*h1.z + w0.w*h1.w;
                a02 += w0.x*h2.x + w0.y*h2.y + w0.z*h2.z + w0.w*h2.w;
                a03 += w0.x*h3.x + w0.y*h3.y + w0.z*h3.z + w0.w*h3.w;
                a10 += w1.x*h0.x + w1.y*h0.y + w1.z*h0.z + w1.w*h0.w;
                a11 += w1.x*h1.x + w1.y*h1.y + w1.z*h1.z + w1.w*h1.w;
                a12 += w1.x*h2.x + w1.y*h2.y + w1.z*h2.z + w1.w*h2.w;
                a13 += w1.x*h3.x + w1.y*h3.y + w1.z*h3.z + w1.w*h3.w;
            }
        }
        // reduce over kh (8-lane butterfly); every lane gets all 8 sums
        #define RED(A) A += __shfl_xor(A,1); A += __shfl_xor(A,2); A += __shfl_xor(A,4);
        RED(a00) RED(a01) RED(a02) RED(a03) RED(a10) RED(a11) RED(a12) RED(a13)
        #undef RED
        {
            int q = kh & 3, rs = kh >> 2;
            float v = (kh == 0) ? a00 : (kh == 1) ? a01 : (kh == 2) ? a02 :
                      (kh == 3) ? a03 : (kh == 4) ? a10 : (kh == 5) ? a11 :
                      (kh == 6) ? a12 : a13;
            sh_g[4 * bh + q][rs ? r1 : r0] = v;
        }
        __syncthreads();   // BARRIER A: gates ready, h_cur reads done, h_em ready

        const int p = it & 1;
        float* hxp = hx + (size_t)p * 65536 + (size_t)cluster * 2048;
        int* tags = tagbuf + p * 256 + cluster * 8;

        if (t < 256) {
            // nonlin + publish
            float iv = sh_g[nb][nd]      + xi;
            float fv = sh_g[nb][32 + nd] + xf;
            float gv = sh_g[nb][64 + nd] + xq;
            float ov = sh_g[nb][96 + nd] + xo;
            float si = 1.f / (1.f + expf(-iv));
            float sf = 1.f / (1.f + expf(-fv));
            float so = 1.f / (1.f + expf(-ov));
            float tg = tanhf(gv);
            c_state = sf * c_state + si * tg;
            float hh = so * tanhf(c_state);
            int dl = myb * 32 + nd;
            int k4w = dl >> 2;
            h_cur[nb][4 * (k4w ^ (k4w >> 3)) + (dl & 3)] = hh;
            __hip_atomic_store(&hxp[nb * 256 + dl], hh,
                               __ATOMIC_RELAXED, __HIP_MEMORY_SCOPE_AGENT);
            asm volatile("s_waitcnt vmcnt(0)" ::: "memory");
            if (lane == 0) atomicAdd(&sh_ctr, 1);
            if (t == 0) {
                while (__hip_atomic_load(&sh_ctr, __ATOMIC_RELAXED,
                                         __HIP_MEMORY_SCOPE_WORKGROUP) < 4 * (it + 1)) {}
                __hip_atomic_store(&tags[myb], it,
                                   __ATOMIC_RELAXED, __HIP_MEMORY_SCOPE_AGENT);
            }
            // xg prefetch for it+1 (issued after publish; completes during next dot)
            if (it < SEQ - 1) {
                int sn = dir ? (SEQ - 2 - it) : (it + 1);
                int id = ids[(oct * 8 + nb) * SEQ + sn];
                const float* tb = table + (size_t)id * 2048 + dir * 1024;
                int base = myb * 32 + nd;
                xi = tb[base]; xf = tb[256 + base]; xq = tb[512 + base]; xo = tb[768 + base];
            }
        } else if (t < 512) {
            // emission for h_{it-1} from linear stash
            if (it > 0 && em < 144) {
                int sp = dir ? (SEQ - it) : (it - 1);
                float pe = 0.f;
                #pragma unroll
                for (int j = 0; j < 16; ++j)
                    pe += wout_s[etg][el + 16 * j] * h_em[el + 16 * j];
                pe += __shfl_xor(pe, 1); pe += __shfl_xor(pe, 2);
                pe += __shfl_xor(pe, 4); pe += __shfl_xor(pe, 8);
                if (el == 0)
                    emp[(((size_t)(dir * BATCH) + gbatch) * SEQ + sp) * NT + etg] = pe;
            }
        } else {
            // per-peer poll + copy
            int j = cw;
            if (j != myb) {
                while (__hip_atomic_load(&tags[j], __ATOMIC_RELAXED,
                                         __HIP_MEMORY_SCOPE_AGENT) != it)
                    __builtin_amdgcn_s_sleep(1);
                #pragma unroll
                for (int rep = 0; rep < 4; ++rep) {
                    int idx = rep * 64 + lane;
                    int nb2 = idx >> 5, nd2 = idx & 31;
                    float v = __hip_atomic_load(&hxp[nb2 * 256 + j * 32 + nd2],
                                                __ATOMIC_RELAXED, __HIP_MEMORY_SCOPE_AGENT);
                    int dl = j * 32 + nd2;
                    int k4w = dl >> 2;
                    h_cur[nb2][4 * (k4w ^ (k4w >> 3)) + (dl & 3)] = v;
                }
            }
        }
        __syncthreads();   // BARRIER B: h_cur = full h_it
    }

    // final emission for h_{511}: stash then emit
    if (t < 256) {
        int k4s = t >> 2;
        h_em[t] = h_cur[myb][4 * (k4s ^ (k4s >> 3)) + (t & 3)];
    }
    __syncthreads();
    if (t < 144) {
        int etg2 = t >> 4, el2 = t & 15;
        int sp = dir ? 0 : (SEQ - 1);
        float pe = 0.f;
        #pragma unroll
        for (int j = 0; j < 16; ++j)
            pe += wout_s[etg2][el2 + 16 * j] * h_em[el2 + 16 * j];
        pe += __shfl_xor(pe, 1); pe += __shfl_xor(pe, 2);
        pe += __shfl_xor(pe, 4); pe += __shfl_xor(pe, 8);
        if (el2 == 0)
            emp[(((size_t)(dir * BATCH) + gbatch) * SEQ + sp) * NT + etg2] = pe;
    }
}

// ---------------- K3: Viterbi decode per batch ----------------
__global__ __launch_bounds__(64) void k_viterbi(
    const float* __restrict__ emp, const float* __restrict__ b_out,
    const float* __restrict__ start_t, const float* __restrict__ end_t,
    const float* __restrict__ trans, const void* __restrict__ maskp,
    const int* __restrict__ mask_is_bool, int* __restrict__ out) {
    __shared__ float sh_em[SEQ][NT];
    __shared__ float sh_score[NT];
    __shared__ float sh_trans[NT * NT];
    __shared__ unsigned char sh_mask[SEQ];
    __shared__ unsigned char sh_hist[SEQ - 1][NT];
    __shared__ unsigned char sh_tags[SEQ];
    int b = blockIdx.x;
    int t = threadIdx.x;
    int isb = *mask_is_bool;
    for (int idx = t; idx < SEQ * NT; idx += 64) {
        int s = idx / NT, tg = idx % NT;
        sh_em[s][tg] = emp[((size_t)b * SEQ + s) * NT + tg]
                     + emp[(((size_t)BATCH + b) * SEQ + s) * NT + tg]
                     + b_out[tg];
    }
    if (isb) {
        const unsigned char* m8 = (const unsigned char*)maskp;
        for (int idx = t; idx < SEQ; idx += 64) sh_mask[idx] = m8[b * SEQ + idx];
    } else {
        const int* m32 = (const int*)maskp;
        for (int idx = t; idx < SEQ; idx += 64) sh_mask[idx] = (unsigned char)(m32[b * SEQ + idx] != 0);
    }
    for (int idx = t; idx < NT * NT; idx += 64) sh_trans[idx] = trans[idx];
    __syncthreads();
    float sc = 0.f;
    if (t < NT) { sc = start_t[t] + sh_em[0][t]; sh_score[t] = sc; }
    __syncthreads();
    for (int s = 1; s < SEQ; ++s) {
        if (t < NT) {
            float m = -3.4e38f; int bp = 0;
            #pragma unroll
            for (int i = 0; i < NT; ++i) {
                float v = sh_score[i] + sh_trans[i * NT + t];
                if (v > m) { m = v; bp = i; }
            }
            sh_hist[s - 1][t] = (unsigned char)bp;
            float best = m + sh_em[s][t];
            if (sh_mask[s]) sc = best;
        }
        __syncthreads();
        if (t < NT) sh_score[t] = sc;
        __syncthreads();
    }
    if (t == 0) {
        float bb = -3.4e38f; int tag = 0;
        for (int j = 0; j < NT; ++j) {
            float v = sh_score[j] + end_t[j];
            if (v > bb) { bb = v; tag = j; }
        }
        for (int pos = SEQ - 1; pos >= 1; --pos) {
            sh_tags[pos] = (unsigned char)tag;
            if (sh_mask[pos]) tag = sh_hist[pos - 1][tag];
        }
        sh_tags[0] = (unsigned char)tag;
    }
    __syncthreads();
    for (int idx = t; idx < SEQ; idx += 64) {
        out[b * SEQ + idx] = sh_mask[idx] ? (int)sh_tags[idx] : 0;
    }
}

extern "C" void kernel_launch(void* const* d_in, const int* in_sizes, int n_in,
                              void* d_out, int out_size, void* d_ws, size_t ws_size,
                              hipStream_t stream) {
    const int*   ids  = (const int*)d_in[0];
    const void*  mask = d_in[1];
    const float* emb  = (const float*)d_in[2];
    const float* Wihf = (const float*)d_in[3];
    const float* Whhf = (const float*)d_in[4];
    const float* bfv  = (const float*)d_in[5];
    const float* Wihb = (const float*)d_in[6];
    const float* Whhb = (const float*)d_in[7];
    const float* bbv  = (const float*)d_in[8];
    const float* Wout = (const float*)d_in[9];
    const float* bout = (const float*)d_in[10];
    const float* st   = (const float*)d_in[11];
    const float* en   = (const float*)d_in[12];
    const float* tr   = (const float*)d_in[13];
    int* out = (int*)d_out;

    char* ws = (char*)d_ws;
    float* table = (float*)ws;                                       // 245,760,000 B
    float* emp   = (float*)(ws + 245760000);                         //   4,718,592 B
    float* hx    = (float*)(ws + 245760000 + 4718592);               //     524,288 B
    int*   tags  = (int*)(ws + 245760000 + 4718592 + 524288);        //       2,048 B
    int*   flag  = (int*)(ws + 245760000 + 4718592 + 524288 + 2048); //           4 B

    k_detect<<<1, 128, 0, stream>>>((const unsigned char*)mask, flag);
    dim3 g1(32, 469);
    k_table_gemm<<<g1, 256, 0, stream>>>(emb, Wihf, Wihb, bfv, bbv, table);
    k_lstm_cl<<<256, 1024, 131072, stream>>>(ids, Whhf, Whhb, table, Wout, emp, hx, tags);
    k_viterbi<<<128, 64, 0, stream>>>(emp, bout, st, en, tr, mask, flag, out);
}

// Round 12
// 4349.189 us; speedup vs baseline: 1.0829x; 1.0829x over previous
//
#include <hip/hip_runtime.h>
#include <hip/hip_bf16.h>

#define SEQ   512
#define BATCH 128
#define VOCAB 30000
#define EDIM  256
#define HDIM  256
#define NT    9

// ---------------- K0b: detect mask storage dtype ----------------
__global__ void k_detect(const unsigned char* __restrict__ m, int* __restrict__ flag) {
    __shared__ int ok_sh;
    if (threadIdx.x == 0) ok_sh = 1;
    __syncthreads();
    int b = threadIdx.x;  // 128 threads, one row each
    const uint4* row = (const uint4*)(m + b * SEQ);
    int ok = 1, prev = 1;
    for (int i = 0; i < SEQ / 16; ++i) {
        uint4 v = row[i];
        unsigned w[4] = {v.x, v.y, v.z, v.w};
        #pragma unroll
        for (int wi = 0; wi < 4; ++wi) {
            #pragma unroll
            for (int j = 0; j < 4; ++j) {
                int byte = (w[wi] >> (8 * j)) & 255;
                if (byte > 1 || byte > prev) ok = 0;
                prev = byte;
            }
        }
    }
    if (!ok) atomicAnd(&ok_sh, 0);
    __syncthreads();
    if (threadIdx.x == 0) *flag = ok_sh;
}

// ---------------- K1: table[v][n] = embed[v] . Wcat[n] + bias[n] ----------------
__global__ __launch_bounds__(256) void k_table_gemm(
    const float* __restrict__ emb, const float* __restrict__ Wf,
    const float* __restrict__ Wb, const float* __restrict__ bf,
    const float* __restrict__ bb, float* __restrict__ table) {
    __shared__ __align__(16) float As[64][68];  // [k][m]
    __shared__ __align__(16) float Bs[64][68];  // [k][n]
    int t  = threadIdx.x;
    int tx = t & 15, ty = t >> 4;
    int n0 = blockIdx.x * 64;
    int v0 = blockIdx.y * 64;
    float acc[4][4] = {};
    for (int kc = 0; kc < 4; ++kc) {
        #pragma unroll
        for (int rr = 0; rr < 4; ++rr) {
            int slot = t + rr * 256;
            int m = slot >> 4, kq = slot & 15;
            int v = v0 + m;
            float4 a = (v < VOCAB)
                ? *(const float4*)&emb[v * EDIM + kc * 64 + kq * 4]
                : make_float4(0.f, 0.f, 0.f, 0.f);
            As[kq * 4 + 0][m] = a.x; As[kq * 4 + 1][m] = a.y;
            As[kq * 4 + 2][m] = a.z; As[kq * 4 + 3][m] = a.w;
            int n = n0 + m;
            const float* Wrow = (n < 1024) ? &Wf[n * 256] : &Wb[(n - 1024) * 256];
            float4 bvec = *(const float4*)&Wrow[kc * 64 + kq * 4];
            Bs[kq * 4 + 0][m] = bvec.x; Bs[kq * 4 + 1][m] = bvec.y;
            Bs[kq * 4 + 2][m] = bvec.z; Bs[kq * 4 + 3][m] = bvec.w;
        }
        __syncthreads();
        #pragma unroll
        for (int k = 0; k < 64; ++k) {
            float4 a = *(const float4*)&As[k][ty * 4];
            float4 b = *(const float4*)&Bs[k][tx * 4];
            acc[0][0] += a.x * b.x; acc[0][1] += a.x * b.y; acc[0][2] += a.x * b.z; acc[0][3] += a.x * b.w;
            acc[1][0] += a.y * b.x; acc[1][1] += a.y * b.y; acc[1][2] += a.y * b.z; acc[1][3] += a.y * b.w;
            acc[2][0] += a.z * b.x; acc[2][1] += a.z * b.y; acc[2][2] += a.z * b.z; acc[2][3] += a.z * b.w;
            acc[3][0] += a.w * b.x; acc[3][1] += a.w * b.y; acc[3][2] += a.w * b.z; acc[3][3] += a.w * b.w;
        }
        __syncthreads();
    }
    int n = n0 + tx * 4;
    const float* bi = (n < 1024) ? &bf[n] : &bb[n - 1024];
    float4 bias = *(const float4*)bi;
    #pragma unroll
    for (int i = 0; i < 4; ++i) {
        int v = v0 + ty * 4 + i;
        if (v < VOCAB) {
            float4 o;
            o.x = acc[i][0] + bias.x; o.y = acc[i][1] + bias.y;
            o.z = acc[i][2] + bias.z; o.w = acc[i][3] + bias.w;
            *(float4*)&table[(size_t)v * 2048 + n] = o;
        }
    }
}

// ---------------- K2: clustered LSTM, W LDS-resident, overlapped L3 exchange --
// 256 blocks x 1024 threads. cluster = bid>>3, myb = bid&7; dir = cluster&1.
// Dot map (R=4 rows, B=8 batches, K4=2 per thread; minimal LDS traffic):
//   half-wave g = t>>5 (0..31) owns rows [g*4, g*4+4); lane kc = t&31 owns
//   k4 in {kc, kc+32}. All reads contiguous per 16-lane phase (2-way = free).
//   W linear sh_w[row][256]; h linear h_cur[b][256]. 24 ds_read_b128/thread.
// Reduction: 5-stage thinning butterfly over the 32 kc lanes; lane kc ends
//   holding the gate sum for tile m = bitrev5(kc): row g*4+(m>>3), batch m&7.
// Exchange (identical to r10/r11, proven): relaxed agent atomics to L3,
//   vmcnt(0), monotonic tags + 2-slot ring; wave roles after barrier A:
//   waves 0-3 nonlin+publish+tag+xg-prefetch, 4-7 emission from h_em stash,
//   8-15 per-peer poll+copy. 2 barriers/step.
__global__ __launch_bounds__(1024) void k_lstm_cl(
    const int* __restrict__ ids, const float* __restrict__ Whhf,
    const float* __restrict__ Whhb, const float* __restrict__ table,
    const float* __restrict__ Wout, float* __restrict__ emp,
    float* hx, int* tagbuf) {
    extern __shared__ float sh_w[];            // [128][256] linear = 128 KB
    __shared__ float h_cur[8][256];            // 8 KB linear
    __shared__ float h_em[256];                // 1 KB stash (batch myb, h_{it-1})
    __shared__ float sh_g[8][128];             // 4 KB gates [batch][gate*32+dim]
    __shared__ float wout_s[NT][257];
    __shared__ int   sh_ctr;

    const int t   = threadIdx.x;
    const int bid = blockIdx.x;
    const int cluster = bid >> 3;
    const int myb = bid & 7;
    const int dir = cluster & 1;
    const int oct = cluster >> 1;
    const int gbatch = oct * 8 + myb;

    const int lane = t & 63;
    const int wv   = t >> 6;
    const int g    = t >> 5;                   // half-wave tile group 0..31
    const int kc   = t & 31;                   // k lane

    const int nb = t >> 5, nd = t & 31;        // nonlin map (t<256)
    const int em = t - 256;                    // emission map (256<=t<400)
    const int etg = em >> 4, el = em & 15;
    const int cw = wv - 8;                     // copy-wave peer id (wv>=8)

    const float* Whh = dir ? Whhb : Whhf;

    if (t == 0) sh_ctr = 0;
    for (int idx = t; idx < NT * 256; idx += 1024)
        wout_s[idx >> 8][idx & 255] = Wout[(idx >> 8) * 512 + dir * 256 + (idx & 255)];
    // stage W-slice (linear): local row lr -> global gate row
    {
        int lr = t >> 3, seg = t & 7;
        int grow = (lr >> 5) * 256 + myb * 32 + (lr & 31);
        const float4* src = (const float4*)(Whh + (size_t)grow * 256) + seg * 8;
        float4* dst = (float4*)(sh_w + lr * 256) + seg * 8;
        #pragma unroll
        for (int i = 0; i < 8; ++i) dst[i] = src[i];
    }
    for (int idx = t; idx < 2048; idx += 1024) ((float*)h_cur)[idx] = 0.f;
    float c_state = 0.f;
    __syncthreads();

    // xg prefetch for it=0 (nonlin threads hold i,f,g,o in regs)
    float xi = 0.f, xf = 0.f, xq = 0.f, xo = 0.f;
    if (t < 256) {
        int s0 = dir ? SEQ - 1 : 0;
        int id = ids[(oct * 8 + nb) * SEQ + s0];
        const float* tb = table + (size_t)id * 2048 + dir * 1024;
        int base = myb * 32 + nd;
        xi = tb[base]; xf = tb[256 + base]; xq = tb[512 + base]; xo = tb[768 + base];
    }

    const float* wbase = sh_w + g * 1024 + 4 * kc;
    const float* hbase = (const float*)h_cur + 4 * kc;

    #pragma unroll 1
    for (int it = 0; it < SEQ; ++it) {
        // ---- stash h_em (linear) + dot ----
        if (t < 256) h_em[t] = h_cur[myb][t];

        float a[32];
        #pragma unroll
        for (int m = 0; m < 32; ++m) a[m] = 0.f;
        #pragma unroll
        for (int j = 0; j < 2; ++j) {
            float4 w0 = *(const float4*)(wbase + 0 * 256 + 128 * j);
            float4 w1 = *(const float4*)(wbase + 1 * 256 + 128 * j);
            float4 w2 = *(const float4*)(wbase + 2 * 256 + 128 * j);
            float4 w3 = *(const float4*)(wbase + 3 * 256 + 128 * j);
            #pragma unroll
            for (int b = 0; b < 8; ++b) {
                float4 hb = *(const float4*)(hbase + b * 256 + 128 * j);
                a[0  + b] += w0.x*hb.x + w0.y*hb.y + w0.z*hb.z + w0.w*hb.w;
                a[8  + b] += w1.x*hb.x + w1.y*hb.y + w1.z*hb.z + w1.w*hb.w;
                a[16 + b] += w2.x*hb.x + w2.y*hb.y + w2.z*hb.z + w2.w*hb.w;
                a[24 + b] += w3.x*hb.x + w3.y*hb.y + w3.z*hb.z + w3.w*hb.w;
            }
        }
        // 5-stage thinning butterfly over kc lanes (width 32, within half-wave)
        #pragma unroll
        for (int m = 0; m < 16; ++m) {
            int bit = kc & 1;
            float sent = bit ? a[m] : a[m + 16];
            float recv = __shfl_xor(sent, 1);
            a[m] = (bit ? a[m + 16] : a[m]) + recv;
        }
        #pragma unroll
        for (int m = 0; m < 8; ++m) {
            int bit = kc & 2;
            float sent = bit ? a[m] : a[m + 8];
            float recv = __shfl_xor(sent, 2);
            a[m] = (bit ? a[m + 8] : a[m]) + recv;
        }
        #pragma unroll
        for (int m = 0; m < 4; ++m) {
            int bit = kc & 4;
            float sent = bit ? a[m] : a[m + 4];
            float recv = __shfl_xor(sent, 4);
            a[m] = (bit ? a[m + 4] : a[m]) + recv;
        }
        #pragma unroll
        for (int m = 0; m < 2; ++m) {
            int bit = kc & 8;
            float sent = bit ? a[m] : a[m + 2];
            float recv = __shfl_xor(sent, 8);
            a[m] = (bit ? a[m + 2] : a[m]) + recv;
        }
        {
            int bit = kc & 16;
            float sent = bit ? a[0] : a[1];
            float recv = __shfl_xor(sent, 16);
            a[0] = (bit ? a[1] : a[0]) + recv;
        }
        {
            // lane kc holds tile m = bitrev5(kc): r = m>>3, b = m&7
            int mfin = ((kc & 1) << 4) | ((kc & 2) << 2) | (kc & 4)
                     | ((kc & 8) >> 2) | ((kc & 16) >> 4);
            sh_g[mfin & 7][g * 4 + (mfin >> 3)] = a[0];
        }
        __syncthreads();   // BARRIER A: gates ready, h_cur reads done, h_em ready

        const int p = it & 1;
        float* hxp = hx + (size_t)p * 65536 + (size_t)cluster * 2048;
        int* tags = tagbuf + p * 256 + cluster * 8;

        if (t < 256) {
            // nonlin + publish
            float iv = sh_g[nb][nd]      + xi;
            float fv = sh_g[nb][32 + nd] + xf;
            float gv = sh_g[nb][64 + nd] + xq;
            float ov = sh_g[nb][96 + nd] + xo;
            float si = 1.f / (1.f + expf(-iv));
            float sf = 1.f / (1.f + expf(-fv));
            float so = 1.f / (1.f + expf(-ov));
            float tg = tanhf(gv);
            c_state = sf * c_state + si * tg;
            float hh = so * tanhf(c_state);
            int dl = myb * 32 + nd;
            h_cur[nb][dl] = hh;
            __hip_atomic_store(&hxp[nb * 256 + dl], hh,
                               __ATOMIC_RELAXED, __HIP_MEMORY_SCOPE_AGENT);
            asm volatile("s_waitcnt vmcnt(0)" ::: "memory");
            if (lane == 0) atomicAdd(&sh_ctr, 1);
            if (t == 0) {
                while (__hip_atomic_load(&sh_ctr, __ATOMIC_RELAXED,
                                         __HIP_MEMORY_SCOPE_WORKGROUP) < 4 * (it + 1)) {}
                __hip_atomic_store(&tags[myb], it,
                                   __ATOMIC_RELAXED, __HIP_MEMORY_SCOPE_AGENT);
            }
            // xg prefetch for it+1
            if (it < SEQ - 1) {
                int sn = dir ? (SEQ - 2 - it) : (it + 1);
                int id = ids[(oct * 8 + nb) * SEQ + sn];
                const float* tb = table + (size_t)id * 2048 + dir * 1024;
                int base = myb * 32 + nd;
                xi = tb[base]; xf = tb[256 + base]; xq = tb[512 + base]; xo = tb[768 + base];
            }
        } else if (t < 512) {
            // emission for h_{it-1} from linear stash
            if (it > 0 && em < 144) {
                int sp = dir ? (SEQ - it) : (it - 1);
                float pe = 0.f;
                #pragma unroll
                for (int j = 0; j < 16; ++j)
                    pe += wout_s[etg][el + 16 * j] * h_em[el + 16 * j];
                pe += __shfl_xor(pe, 1); pe += __shfl_xor(pe, 2);
                pe += __shfl_xor(pe, 4); pe += __shfl_xor(pe, 8);
                if (el == 0)
                    emp[(((size_t)(dir * BATCH) + gbatch) * SEQ + sp) * NT + etg] = pe;
            }
        } else {
            // per-peer poll + copy
            int j = cw;
            if (j != myb) {
                while (__hip_atomic_load(&tags[j], __ATOMIC_RELAXED,
                                         __HIP_MEMORY_SCOPE_AGENT) != it)
                    __builtin_amdgcn_s_sleep(1);
                #pragma unroll
                for (int rep = 0; rep < 4; ++rep) {
                    int idx = rep * 64 + lane;
                    int nb2 = idx >> 5, nd2 = idx & 31;
                    float v = __hip_atomic_load(&hxp[nb2 * 256 + j * 32 + nd2],
                                                __ATOMIC_RELAXED, __HIP_MEMORY_SCOPE_AGENT);
                    h_cur[nb2][j * 32 + nd2] = v;
                }
            }
        }
        __syncthreads();   // BARRIER B: h_cur = full h_it
    }

    // final emission for h_{511}: stash then emit
    if (t < 256) h_em[t] = h_cur[myb][t];
    __syncthreads();
    if (t < 144) {
        int etg2 = t >> 4, el2 = t & 15;
        int sp = dir ? 0 : (SEQ - 1);
        float pe = 0.f;
        #pragma unroll
        for (int j = 0; j < 16; ++j)
            pe += wout_s[etg2][el2 + 16 * j] * h_em[el2 + 16 * j];
        pe += __shfl_xor(pe, 1); pe += __shfl_xor(pe, 2);
        pe += __shfl_xor(pe, 4); pe += __shfl_xor(pe, 8);
        if (el2 == 0)
            emp[(((size_t)(dir * BATCH) + gbatch) * SEQ + sp) * NT + etg2] = pe;
    }
}

// ---------------- K3: Viterbi decode per batch ----------------
__global__ __launch_bounds__(64) void k_viterbi(
    const float* __restrict__ emp, const float* __restrict__ b_out,
    const float* __restrict__ start_t, const float* __restrict__ end_t,
    const float* __restrict__ trans, const void* __restrict__ maskp,
    const int* __restrict__ mask_is_bool, int* __restrict__ out) {
    __shared__ float sh_em[SEQ][NT];
    __shared__ float sh_score[NT];
    __shared__ float sh_trans[NT * NT];
    __shared__ unsigned char sh_mask[SEQ];
    __shared__ unsigned char sh_hist[SEQ - 1][NT];
    __shared__ unsigned char sh_tags[SEQ];
    int b = blockIdx.x;
    int t = threadIdx.x;
    int isb = *mask_is_bool;
    for (int idx = t; idx < SEQ * NT; idx += 64) {
        int s = idx / NT, tg = idx % NT;
        sh_em[s][tg] = emp[((size_t)b * SEQ + s) * NT + tg]
                     + emp[(((size_t)BATCH + b) * SEQ + s) * NT + tg]
                     + b_out[tg];
    }
    if (isb) {
        const unsigned char* m8 = (const unsigned char*)maskp;
        for (int idx = t; idx < SEQ; idx += 64) sh_mask[idx] = m8[b * SEQ + idx];
    } else {
        const int* m32 = (const int*)maskp;
        for (int idx = t; idx < SEQ; idx += 64) sh_mask[idx] = (unsigned char)(m32[b * SEQ + idx] != 0);
    }
    for (int idx = t; idx < NT * NT; idx += 64) sh_trans[idx] = trans[idx];
    __syncthreads();
    float sc = 0.f;
    if (t < NT) { sc = start_t[t] + sh_em[0][t]; sh_score[t] = sc; }
    __syncthreads();
    for (int s = 1; s < SEQ; ++s) {
        if (t < NT) {
            float m = -3.4e38f; int bp = 0;
            #pragma unroll
            for (int i = 0; i < NT; ++i) {
                float v = sh_score[i] + sh_trans[i * NT + t];
                if (v > m) { m = v; bp = i; }
            }
            sh_hist[s - 1][t] = (unsigned char)bp;
            float best = m + sh_em[s][t];
            if (sh_mask[s]) sc = best;
        }
        __syncthreads();
        if (t < NT) sh_score[t] = sc;
        __syncthreads();
    }
    if (t == 0) {
        float bb = -3.4e38f; int tag = 0;
        for (int j = 0; j < NT; ++j) {
            float v = sh_score[j] + end_t[j];
            if (v > bb) { bb = v; tag = j; }
        }
        for (int pos = SEQ - 1; pos >= 1; --pos) {
            sh_tags[pos] = (unsigned char)tag;
            if (sh_mask[pos]) tag = sh_hist[pos - 1][tag];
        }
        sh_tags[0] = (unsigned char)tag;
    }
    __syncthreads();
    for (int idx = t; idx < SEQ; idx += 64) {
        out[b * SEQ + idx] = sh_mask[idx] ? (int)sh_tags[idx] : 0;
    }
}

extern "C" void kernel_launch(void* const* d_in, const int* in_sizes, int n_in,
                              void* d_out, int out_size, void* d_ws, size_t ws_size,
                              hipStream_t stream) {
    const int*   ids  = (const int*)d_in[0];
    const void*  mask = d_in[1];
    const float* emb  = (const float*)d_in[2];
    const float* Wihf = (const float*)d_in[3];
    const float* Whhf = (const float*)d_in[4];
    const float* bfv  = (const float*)d_in[5];
    const float* Wihb = (const float*)d_in[6];
    const float* Whhb = (const float*)d_in[7];
    const float* bbv  = (const float*)d_in[8];
    const float* Wout = (const float*)d_in[9];
    const float* bout = (const float*)d_in[10];
    const float* st   = (const float*)d_in[11];
    const float* en   = (const float*)d_in[12];
    const float* tr   = (const float*)d_in[13];
    int* out = (int*)d_out;

    char* ws = (char*)d_ws;
    float* table = (float*)ws;                                       // 245,760,000 B
    float* emp   = (float*)(ws + 245760000);                         //   4,718,592 B
    float* hx    = (float*)(ws + 245760000 + 4718592);               //     524,288 B
    int*   tags  = (int*)(ws + 245760000 + 4718592 + 524288);        //       2,048 B
    int*   flag  = (int*)(ws + 245760000 + 4718592 + 524288 + 2048); //           4 B

    k_detect<<<1, 128, 0, stream>>>((const unsigned char*)mask, flag);
    dim3 g1(32, 469);
    k_table_gemm<<<g1, 256, 0, stream>>>(emb, Wihf, Wihb, bfv, bbv, table);
    k_lstm_cl<<<256, 1024, 131072, stream>>>(ids, Whhf, Whhb, table, Wout, emp, hx, tags);
    k_viterbi<<<128, 64, 0, stream>>>(emp, bout, st, en, tr, mask, flag, out);
}